// Round 13
// baseline (38.864 us; speedup 1.0000x reference)
//
#include <hip/hip_runtime.h>

#define NL 17
#define IGN (-100)
#define HD 384
#define NSEQ 1024
#define NT 65536
#define BIGI NT
#define TPB 256
#define NBLK (NT / TPB)        // 256
#define NCHUNK 6               // 384 / 64 cols
#define CF4 16                 // float4 per row per chunk (64 cols)
#define WPAD 392               // u16 row stride for bf16 W

typedef unsigned int u32;
typedef unsigned short u16;
typedef __attribute__((ext_vector_type(8))) short bf16x8;
typedef __attribute__((ext_vector_type(16))) float f32x16;

#define GLOAD_LDS16(g, l) __builtin_amdgcn_global_load_lds(                    \
    (const __attribute__((address_space(1))) u32*)(g),                         \
    (__attribute__((address_space(3))) u32*)(l), 16, 0, 0)

__device__ __forceinline__ u32 cvtpk(float lo, float hi) {
  u32 u;
  asm("v_cvt_pk_bf16_f32 %0, %1, %2" : "=v"(u) : "v"(lo), "v"(hi));
  return u;
}

struct WS {
  float ce_part[NBLK];
  float ctx_part[NBLK];
  int   ce_cnt[NBLK];
  int   ctx_cnt[NBLK];
  int   blk_a[NBLK][16];
  int   blk_p[NBLK][16];
  int   blk_c[NBLK][16];
  int   blk_d[NBLK];
};

// ---- main: per-wave private 64-col double-buffer, barrier-free stream loop ----
__global__ __launch_bounds__(256, 1) void k_main(const float* __restrict__ emb,
                                                 const float* __restrict__ cw,
                                                 const float* __restrict__ cb,
                                                 const int* __restrict__ labels,
                                                 const int* __restrict__ mask,
                                                 WS* __restrict__ ws) {
  __shared__ float4 tile[2][4][1024];   // [buf][wave][64 rows x 16 f4] = 128 KB
  __shared__ u16    sWh[NL * WPAD];     // 13.3 KB W in bf16
  __shared__ float  sce[4], sctx[4];
  __shared__ int    svc[4], spc[4];
  __shared__ int    sla[16], slp[16], slc[16], sld;

  const int tid = threadIdx.x, lane = tid & 63, wid = tid >> 6;
  const int uwid = __builtin_amdgcn_readfirstlane(wid);
  const int b = blockIdx.x;
  const int token = b * TPB + tid;

  // ---- W -> LDS as bf16 (once); scan init ----
  for (int i = tid; i < NL * (HD / 2); i += TPB) {
    int c = i / (HD / 2), p = i % (HD / 2);
    u32 pk = cvtpk(cw[c * HD + 2 * p], cw[c * HD + 2 * p + 1]);
    *(u32*)&sWh[c * WPAD + 2 * p] = pk;
  }
  if (tid < 16) { sla[tid] = BIGI; slp[tid] = BIGI; slc[tid] = 0; }
  if (tid == 16) sld = BIGI;
  __syncthreads();   // drains all VMEM -> manual vmcnt counting is exact

  // ---- per-wave staging geometry ----
  // load k (k=0..15) covers local rows k*4..k*4+3; lane: row = k*4 + (lane>>4),
  // LDS slot f4 = lane&15, holding logical col (lane&15) ^ (row&7)
  const int l4  = lane >> 4;                 // 0..3
  const int c16 = lane & 15;
  const float* srcE = emb + ((size_t)b * TPB + wid * 64 + l4) * HD + ((c16 ^ l4) << 2);
  const float* srcO = emb + ((size_t)b * TPB + wid * 64 + l4) * HD + ((c16 ^ (4 + l4)) << 2);

  auto issue = [&](int c) {
    const float* sE = srcE + (size_t)c * 64;
    const float* sO = srcO + (size_t)c * 64;
    float4* d = &tile[c & 1][uwid][0];
#pragma unroll
    for (int k = 0; k < CF4; ++k) {
      const float* s = (k & 1) ? sO : sE;
      GLOAD_LDS16(s + (size_t)k * 4 * HD, &d[k * 64]);
    }
  };

  issue(0); issue(1);   // 32 outstanding per wave

  // ---- MFMA / ctx geometry (local rows within the wave's 64-row tile) ----
  const int cls = lane & 31;
  const int kh  = lane >> 5;
  const int clsS = (cls < NL) ? cls : 0;
  const int rl0 = lane & 31;                 // B tile0 local row
  const int rl1 = 32 + (lane & 31);          // B tile1 local row
  const int cr0 = lane;                      // ctx own local row
  const int cr1 = (lane < 63) ? lane + 1 : 63;

  f32x16 d0 = {0.f}, d1 = {0.f};
  float ctxacc = 0.f;

  auto afrag = [&](int ch, int s) -> bf16x8 {
    if (cls < NL)
      return *(const bf16x8*)&sWh[clsS * WPAD + ch * 64 + s * 16 + kh * 8];
    union { u32 u[4]; bf16x8 v; } Z;
    Z.u[0] = 0; Z.u[1] = 0; Z.u[2] = 0; Z.u[3] = 0;
    return Z.v;
  };
  auto bfrag = [&](const float4* tb, int row, int s) -> bf16x8 {
    int g0 = (s * 4 + kh * 2) ^ (row & 7);
    int g1 = (s * 4 + kh * 2 + 1) ^ (row & 7);
    float4 f0 = tb[(row << 4) | g0];
    float4 f1 = tb[(row << 4) | g1];
    union { u32 u[4]; bf16x8 v; } X;
    X.u[0] = cvtpk(f0.x, f0.y); X.u[1] = cvtpk(f0.z, f0.w);
    X.u[2] = cvtpk(f1.x, f1.y); X.u[3] = cvtpk(f1.z, f1.w);
    return X.v;
  };

  auto compute = [&](int ch) {
    const float4* tb = (const float4*)&tile[ch & 1][wid][0];
#pragma unroll
    for (int q = 0; q < CF4; ++q) {
      float4 a  = tb[(cr0 << 4) | (q ^ (cr0 & 7))];
      float4 nb = tb[(cr1 << 4) | (q ^ (cr1 & 7))];
      float e0 = a.x - nb.x, e1 = a.y - nb.y, e2 = a.z - nb.z, e3 = a.w - nb.w;
      ctxacc = fmaf(e0, e0, fmaf(e1, e1, fmaf(e2, e2, fmaf(e3, e3, ctxacc))));
    }
#pragma unroll
    for (int s = 0; s < 4; ++s) {
      bf16x8 as = afrag(ch, s);
      bf16x8 b0 = bfrag(tb, rl0, s);
      bf16x8 b1 = bfrag(tb, rl1, s);
      d0 = __builtin_amdgcn_mfma_f32_32x32x16_bf16(as, b0, d0, 0, 0, 0);
      d1 = __builtin_amdgcn_mfma_f32_32x32x16_bf16(as, b1, d1, 0, 0, 0);
    }
  };

  // stream loop: barrier-free, per-wave self-timed
#pragma unroll 1
  for (int ch = 0; ch <= NCHUNK - 3; ++ch) {
    asm volatile("s_waitcnt vmcnt(16)" ::: "memory");   // chunk ch landed
    __builtin_amdgcn_sched_barrier(0);
    compute(ch);
    issue(ch + 2);   // overwrites buf ch&1: this wave just finished reading it
  }
  asm volatile("s_waitcnt vmcnt(16)" ::: "memory");
  __builtin_amdgcn_sched_barrier(0);
  compute(NCHUNK - 2);
  asm volatile("s_waitcnt vmcnt(0)" ::: "memory");
  __builtin_amdgcn_sched_barrier(0);
  compute(NCHUNK - 1);

  __syncthreads();   // all waves done with private tiles -> reuse LDS

  // ---- logits [256][21] over tile[0] ----
  float* logit = (float*)&tile[0][0][0];
#pragma unroll
  for (int r = 0; r < 16; ++r) {
    int row = (r & 3) + 8 * (r >> 2) + 4 * kh;   // class
    if (row < NL) {
      logit[(wid * 64 + (lane & 31)) * 21 + row] = d0[r];
      logit[(wid * 64 + 32 + (lane & 31)) * 21 + row] = d1[r];
    }
  }
  __syncthreads();

  // ---- fused label scan ----
  int lb = labels[token];
  int mk = mask[token];
  int lbm = (mk > 0) ? lb : IGN;
  if (lbm == 0) atomicMin(&sld, token);
  else if (lbm >= 1 && lbm < NL) { atomicMin(&sla[lbm - 1], token); atomicAdd(&slc[lbm - 1], 1); }
  __syncthreads();
  if (lbm >= 1 && lbm < NL && token > sla[lbm - 1]) atomicMin(&slp[lbm - 1], token);

  // ---- softmax + CE + ctx pair ----
  float lg[NL];
#pragma unroll
  for (int c = 0; c < NL; ++c) lg[c] = logit[tid * 21 + c] + cb[c];
  float m = lg[0];
#pragma unroll
  for (int c = 1; c < NL; ++c) m = fmaxf(m, lg[c]);
  float s = 0.f;
#pragma unroll
  for (int c = 0; c < NL; ++c) s += __expf(lg[c] - m);
  float lse = m + __logf(s);
  int safe = (lb == IGN) ? 0 : lb;
  float ll = 0.f;
#pragma unroll
  for (int c = 0; c < NL; ++c) ll = (c == safe) ? lg[c] : ll;
  bool valid = (lb != IGN);
  float cev = valid ? (lse - ll) : 0.f;

  int nlb = (lane < 63) ? labels[token + 1] : IGN;
  bool pair = (lane < 63) && valid && (lb == nlb) && (lb > 0);
  float ctxv = pair ? ctxacc * (1.0f / HD) : 0.f;

  unsigned long long bv = __ballot(valid);
  unsigned long long bp = __ballot(pair);
#pragma unroll
  for (int off = 32; off; off >>= 1) {
    cev  += __shfl_xor(cev, off, 64);
    ctxv += __shfl_xor(ctxv, off, 64);
  }

  // ---- per-wave boundary pair (token w*64+63, +1) via global reads ----
  float bc = 0.f; int bn = 0;
  {
    int t = b * TPB + wid * 64 + 63;
    if (((t + 1) & (NSEQ - 1)) != 0) {
      int l0 = labels[t], l1 = labels[t + 1];
      if (l0 != IGN && l0 == l1 && l0 > 0) {
        const float* ra = emb + (size_t)t * HD;
        const float* rbp = ra + HD;
        float a = 0.f;
#pragma unroll
        for (int j = 0; j < 6; ++j) {
          float dd = ra[lane + 64 * j] - rbp[lane + 64 * j];
          a = fmaf(dd, dd, a);
        }
#pragma unroll
        for (int off = 32; off; off >>= 1) a += __shfl_xor(a, off, 64);
        bc = a * (1.0f / HD); bn = 1;
      }
    }
  }
  if (lane == 0) {
    sce[wid]  = cev;
    sctx[wid] = ctxv + bc;
    svc[wid]  = __popcll(bv);
    spc[wid]  = __popcll(bp) + bn;
  }
  __syncthreads();
  if (tid < 16) {
    ws->blk_a[b][tid] = sla[tid];
    ws->blk_p[b][tid] = slp[tid];
    ws->blk_c[b][tid] = slc[tid];
  }
  if (tid == 16) ws->blk_d[b] = sld;
  if (tid == 0) {
    ws->ce_part[b]  = sce[0] + sce[1] + sce[2] + sce[3];
    ws->ce_cnt[b]   = svc[0] + svc[1] + svc[2] + svc[3];
    ws->ctx_part[b] = sctx[0] + sctx[1] + sctx[2] + sctx[3];
    ws->ctx_cnt[b]  = spc[0] + spc[1] + spc[2] + spc[3];
  }
}

// ---------------- finalize (r10 verbatim) ----------------
__global__ __launch_bounds__(256) void k_final(const float* __restrict__ emb,
                                               WS* __restrict__ ws,
                                               float* __restrict__ out) {
  __shared__ double rce[256], rctx[256];
  __shared__ int rvc[256], rpc[256], rd[256];
  __shared__ int M1[256], M2[256], CN[256];
  __shared__ int ga[16], gp[16], gc[16];
  __shared__ float qs[4]; __shared__ int qc[4];
  const int tid = threadIdx.x, lane = tid & 63, wid = tid >> 6;

  rce[tid]  = ws->ce_part[tid];
  rctx[tid] = ws->ctx_part[tid];
  rvc[tid]  = ws->ce_cnt[tid];
  rpc[tid]  = ws->ctx_cnt[tid];
  rd[tid]   = ws->blk_d[tid];

  {
    const int type = tid & 15, seg = tid >> 4;
    int m1 = BIGI, m2 = BIGI, cnt = 0;
#pragma unroll 4
    for (int k = 0; k < 16; ++k) {
      int bb = seg * 16 + k;
      int x = ws->blk_a[bb][type];
      if (x < m1) { m2 = m1; m1 = x; } else if (x < m2) { m2 = x; }
      int y = ws->blk_p[bb][type];
      if (y < m1) { m2 = m1; m1 = y; } else if (y < m2) { m2 = y; }
      cnt += ws->blk_c[bb][type];
    }
    M1[tid] = m1; M2[tid] = m2; CN[tid] = cnt;
  }
  __syncthreads();
  for (int s = 128; s > 0; s >>= 1) {
    if (tid < s) {
      rce[tid] += rce[tid + s]; rctx[tid] += rctx[tid + s];
      rvc[tid] += rvc[tid + s]; rpc[tid] += rpc[tid + s];
      rd[tid] = min(rd[tid], rd[tid + s]);
    }
    __syncthreads();
  }
  if (tid < 16) {
    int m1 = BIGI, m2 = BIGI, cnt = 0;
    for (int seg = 0; seg < 16; ++seg) {
      int a1 = M1[seg * 16 + tid], a2 = M2[seg * 16 + tid];
      int n1 = min(m1, a1);
      int n2 = min(max(m1, a1), min(m2, a2));
      m1 = n1; m2 = n2;
      cnt += CN[seg * 16 + tid];
    }
    ga[tid] = m1; gp[tid] = m2; gc[tid] = cnt;
  }
  __syncthreads();

  const int gd = rd[0];
  float qsum = 0.f; int qcnt = 0;
  for (int tt = 0; tt < 4; ++tt) {
    int t = wid * 4 + tt;
    int a = ga[t], p = gp[t], c = gc[t];
    int nmin = BIGI;
#pragma unroll
    for (int u = 0; u < 16; ++u) if (u != t) nmin = min(nmin, ga[u]);
    bool ok = (c >= 2) && (nmin < BIGI) && (gd < BIGI);
    if (ok) {
      const float* A  = emb + (size_t)min(a, NT - 1) * HD;
      const float* P  = emb + (size_t)min(p, NT - 1) * HD;
      const float* Ng = emb + (size_t)min(nmin, NT - 1) * HD;
      const float* D  = emb + (size_t)min(gd, NT - 1) * HD;
      float sap = 0.f, san = 0.f, sad = 0.f;
#pragma unroll
      for (int j = 0; j < 6; ++j) {
        int idx = lane + 64 * j;
        float av = A[idx];
        float d1 = av - P[idx] + 1e-6f;  sap = fmaf(d1, d1, sap);
        float d2 = av - Ng[idx] + 1e-6f; san = fmaf(d2, d2, san);
        float d3 = av - D[idx] + 1e-6f;  sad = fmaf(d3, d3, sad);
      }
#pragma unroll
      for (int off = 32; off; off >>= 1) {
        sap += __shfl_xor(sap, off, 64);
        san += __shfl_xor(san, off, 64);
        sad += __shfl_xor(sad, off, 64);
      }
      float pd = sqrtf(sap), nd = sqrtf(san), dd = sqrtf(sad);
      qsum += fmaxf(pd - nd + 1.0f, 0.f) + fmaxf(pd - dd + 2.0f, 0.f);
      qcnt += 1;
    }
  }
  if (lane == 0) { qs[wid] = qsum; qc[wid] = qcnt; }
  __syncthreads();
  if (tid == 0) {
    double tq = (double)qs[0] + qs[1] + qs[2] + qs[3];
    int tqc = qc[0] + qc[1] + qc[2] + qc[3];
    double ce   = rce[0] / (double)max(rvc[0], 1);
    double ctx  = (rpc[0] > 0) ? rctx[0] / (double)rpc[0] : 0.0;
    double quad = (tqc > 0) ? tq / (double)tqc : 0.0;
    out[0] = (float)(ce + 0.5 * quad + 0.1 * ctx);
  }
}

extern "C" void kernel_launch(void* const* d_in, const int* in_sizes, int n_in,
                              void* d_out, int out_size, void* d_ws, size_t ws_size,
                              hipStream_t stream) {
  const float* emb    = (const float*)d_in[0];
  const float* cw     = (const float*)d_in[1];
  const float* cb     = (const float*)d_in[2];
  const int*   labels = (const int*)d_in[3];
  const int*   mask   = (const int*)d_in[4];
  WS* ws = (WS*)d_ws;
  float* out = (float*)d_out;

  k_main <<<NBLK, TPB, 0, stream>>>(emb, cw, cb, labels, mask, ws);
  k_final<<<1, 256, 0, stream>>>(emb, ws, out);
}